// Round 2
// baseline (698.544 us; speedup 1.0000x reference)
//
#include <hip/hip_runtime.h>
#include <hip/hip_bf16.h>
#include <math.h>

#define Bn 128
#define Cn 64
#define Tn 500

// ---------------------------------------------------------------------------
// zero the SE accumulators (ws is poisoned 0xAA before every call)
__global__ void init_kernel(float* p) { p[threadIdx.x] = 0.f; }

// ---------------------------------------------------------------------------
// Stage 1: EEG feature extractor. One block per (b,c) signal.
// Thread mapping: o = tid&15 (channel, fixed per thread -> weights in regs),
// t = tid>>4 + 16*i. LDS reads are 16-lane broadcasts (free), writes 2-way
// conflicts (free per m136). sB doubles as the x staging buffer.
__global__ __launch_bounds__(256) void feat_kernel(
    const float* __restrict__ x, const float* __restrict__ w_conv1,
    const float* __restrict__ bn1, const float* __restrict__ w_dw,
    const float* __restrict__ bn2, const float* __restrict__ w_sdw,
    const float* __restrict__ w_spw, const float* __restrict__ bn3,
    float* __restrict__ feats)
{
  __shared__ float sA[16 * Tn];
  __shared__ float sB[16 * Tn];   // first 500 floats also hold x
  const int n = blockIdx.x;       // 0..8191 = b*64+c
  const int tid = threadIdx.x;
  const int o = tid & 15;
  const int tq = tid >> 4;

  for (int j = tid; j < Tn; j += 256) sB[j] = x[n * Tn + j];

  float w1[25];
#pragma unroll
  for (int k = 0; k < 25; ++k) w1[k] = w_conv1[o * 25 + k];
  float g1 = bn1[o], be1 = bn1[16 + o], m1 = bn1[32 + o], v1 = bn1[48 + o];
  float s1 = g1 / sqrtf(v1 + 1e-5f), sh1 = be1 - m1 * s1;

  __syncthreads();
  // conv1 (K=25, pad 12) + BN + ELU -> sA
  for (int t = tq; t < Tn; t += 16) {
    float acc = 0.f;
    if (t >= 12 && t < Tn - 12) {
#pragma unroll
      for (int k = 0; k < 25; ++k) acc += sB[t + k - 12] * w1[k];
    } else {
#pragma unroll
      for (int k = 0; k < 25; ++k) {
        int ix = t + k - 12;
        if (ix >= 0 && ix < Tn) acc += sB[ix] * w1[k];
      }
    }
    float v = acc * s1 + sh1;
    sA[o * Tn + t] = v > 0.f ? v : expm1f(v);   // jax.nn.elu uses expm1
  }

  float wd[3];
#pragma unroll
  for (int k = 0; k < 3; ++k) wd[k] = w_dw[o * 3 + k];
  float g2 = bn2[o], be2 = bn2[16 + o], m2 = bn2[32 + o], v2 = bn2[48 + o];
  float s2 = g2 / sqrtf(v2 + 1e-5f), sh2 = be2 - m2 * s2;
  __syncthreads();
  // depthwise conv (K=3, pad 1) + BN + ELU -> sB (x staging is dead)
  for (int t = tq; t < Tn; t += 16) {
    float acc = 0.f;
#pragma unroll
    for (int k = 0; k < 3; ++k) {
      int ix = t + k - 1;
      if (ix >= 0 && ix < Tn) acc += sA[o * Tn + ix] * wd[k];
    }
    float v = acc * s2 + sh2;
    sB[o * Tn + t] = v > 0.f ? v : expm1f(v);
  }

  float ws3[3];
#pragma unroll
  for (int k = 0; k < 3; ++k) ws3[k] = w_sdw[o * 3 + k];
  __syncthreads();
  // separable depthwise (K=3, pad 1), no activation -> sA
  for (int t = tq; t < Tn; t += 16) {
    float acc = 0.f;
#pragma unroll
    for (int k = 0; k < 3; ++k) {
      int ix = t + k - 1;
      if (ix >= 0 && ix < Tn) acc += sB[o * Tn + ix] * ws3[k];
    }
    sA[o * Tn + t] = acc;
  }

  float wp[16];
#pragma unroll
  for (int q = 0; q < 16; ++q) wp[q] = w_spw[o * 16 + q];
  float g3 = bn3[o], be3 = bn3[16 + o], m3 = bn3[32 + o], v3 = bn3[48 + o];
  float s3 = g3 / sqrtf(v3 + 1e-5f), sh3 = be3 - m3 * s3;
  __syncthreads();
  // pointwise 16->16 + BN + ELU, then mean over t (AvgPool(4)+mean == mean, 500=4*125)
  float sum = 0.f;
  for (int t = tq; t < Tn; t += 16) {
    float acc = 0.f;
#pragma unroll
    for (int q = 0; q < 16; ++q) acc += sA[q * Tn + t] * wp[q];
    float v = acc * s3 + sh3;
    sum += (v > 0.f ? v : expm1f(v));
  }
  sum += __shfl_xor(sum, 16, 64);
  sum += __shfl_xor(sum, 32, 64);
  __syncthreads();                // sB dead; reuse first 64 floats for reduction
  if ((tid & 63) < 16) sB[(tid >> 6) * 16 + o] = sum;
  __syncthreads();
  if (tid < 16) {
    float tot = sB[tid] + sB[16 + tid] + sB[32 + tid] + sB[48 + tid];
    feats[n * 16 + tid] = tot * (1.f / 500.f);
  }
}

// ---------------------------------------------------------------------------
// Graph construction: Mlog[i][j] = log(M) if M>0 else -inf   (64x64)
__global__ __launch_bounds__(256) void graph_kernel(
    const float* __restrict__ node_embed, const int* __restrict__ edges,
    float* __restrict__ Mlog)
{
  __shared__ float ne[64 * 16];
  __shared__ float Arow[64 * 64];
  __shared__ float Ms[64 * 64];
  __shared__ float rs[64];
  const int tid = threadIdx.x;
  for (int idx = tid; idx < 64 * 16; idx += 256) ne[idx] = node_embed[idx];
  for (int idx = tid; idx < 4096; idx += 256) Ms[idx] = 0.f;
  __syncthreads();
  for (int idx = tid; idx < 4096; idx += 256) {
    int i = idx >> 6, j = idx & 63;
    float a = 0.f;
#pragma unroll
    for (int f = 0; f < 16; ++f) a += ne[i * 16 + f] * ne[j * 16 + f];
    Arow[idx] = a > 0.f ? a : 0.f;
  }
  {
    int e0 = edges[tid];          // 256 threads, 256 edges
    int e1 = edges[256 + tid];
    __syncthreads();
    atomicAdd(&Ms[e0 * 64 + e1], 1.f);
  }
  __syncthreads();
  if (tid < 64) {
    float s = 0.f;
    for (int j = 0; j < 64; ++j) s += Arow[tid * 64 + j];
    rs[tid] = s + 1e-6f;
  }
  __syncthreads();
  for (int idx = tid; idx < 4096; idx += 256) {
    int i = idx >> 6, j = idx & 63;
    float dyn = (Arow[idx] / rs[i] > 0.1f) ? 1.f : 0.f;
    float M = (i == j) ? 1.f : (Ms[idx] + dyn);
    Mlog[idx] = (M > 0.f) ? logf(M) : -INFINITY;
  }
}

// ---------------------------------------------------------------------------
// One GAT layer fused with BN + skip + GELU + SE partial sums. Block per b.
// LAYER==1: X = feats [64x16], skip = X @ skip_w^T
// LAYER==2: X = tmp1 * gate [64x32], skip = X (identity)
template <int FIN, int LAYER>
__global__ __launch_bounds__(256) void gat_kernel(
    const float* __restrict__ Xsrc, const float* __restrict__ gate,
    const float* __restrict__ W, const float* __restrict__ a_src,
    const float* __restrict__ a_dst, const float* __restrict__ bias,
    const float* __restrict__ bnp, const float* __restrict__ skip_w,
    const float* __restrict__ Mlog,
    float* __restrict__ out, float* __restrict__ gsum)
{
  __shared__ float Xs[64 * FIN];
  __shared__ float xls[64 * 132];   // pitch 132: float4-aligned, breaks pow2 strides
  __shared__ float sS[64 * 4];
  __shared__ float dS[64 * 4];
  __shared__ float al[64 * 68];
  __shared__ float pm[256];
  __shared__ float rm[64];
  __shared__ float ps[256];
  __shared__ float inv[64];
  __shared__ float seacc[32];
  const int b = blockIdx.x;
  const int tid = threadIdx.x;

  if (tid < 32) seacc[tid] = 0.f;
  for (int idx = tid; idx < 64 * FIN; idx += 256) {
    float v = Xsrc[b * 64 * FIN + idx];
    if (LAYER == 2) v *= gate[idx % FIN];
    Xs[idx] = v;
  }
  __syncthreads();

  // xl[n][h*32+g] = X[n][:] . W[:][h*32+g]; W column cached in registers
  {
    const int fo = tid & 127, half = tid >> 7;
    float wcol[FIN];
#pragma unroll
    for (int q = 0; q < FIN; ++q) wcol[q] = W[q * 128 + fo];
    for (int nn = half; nn < 64; nn += 2) {
      float acc = 0.f;
#pragma unroll
      for (int q = 0; q < FIN; ++q) acc += Xs[nn * FIN + q] * wcol[q];
      xls[nn * 132 + fo] = acc;
    }
  }
  __syncthreads();

  // attention source/dest terms: thread t -> (n = t>>2, h = t&3)
  {
    const int nn = tid >> 2, h = tid & 3;
    float s = 0.f, d = 0.f;
    for (int q = 0; q < 32; ++q) {
      float xv = xls[nn * 132 + h * 32 + q];
      s += xv * a_src[h * 32 + q];
      d += xv * a_dst[h * 32 + q];
    }
    sS[nn * 4 + h] = s;
    dS[nn * 4 + h] = d;
  }

  float accH[2][4];
#pragma unroll
  for (int ii = 0; ii < 2; ++ii)
#pragma unroll
    for (int r = 0; r < 4; ++r) accH[ii][r] = 0.f;

  const int q4 = tid & 7;   // f quad: channels 4*q4..4*q4+3
  const int ig = tid >> 3;  // i pair:  rows 2*ig, 2*ig+1

  for (int h = 0; h < 4; ++h) {
    __syncthreads();
    // masked logits with multiplicity bias
    for (int idx = tid; idx < 4096; idx += 256) {
      int i = idx >> 6, j = idx & 63;
      float e = dS[i * 4 + h] + sS[j * 4 + h];
      e = e >= 0.f ? e : 0.2f * e;            // leaky_relu(., 0.2)
      al[i * 68 + j] = e + Mlog[idx];         // -inf where masked
    }
    __syncthreads();
    {
      const int i = tid >> 2, c = tid & 3;
      float mx = -INFINITY;
      for (int jj = 0; jj < 16; ++jj) mx = fmaxf(mx, al[i * 68 + c * 16 + jj]);
      pm[tid] = mx;
    }
    __syncthreads();
    if (tid < 64)
      rm[tid] = fmaxf(fmaxf(pm[tid * 4], pm[tid * 4 + 1]),
                      fmaxf(pm[tid * 4 + 2], pm[tid * 4 + 3]));
    __syncthreads();
    {
      const int i = tid >> 2, c = tid & 3;
      float r = rm[i], sm = 0.f;
      for (int jj = 0; jj < 16; ++jj) {
        float v = expf(al[i * 68 + c * 16 + jj] - r);
        al[i * 68 + c * 16 + jj] = v;
        sm += v;
      }
      ps[tid] = sm;
    }
    __syncthreads();
    if (tid < 64)
      inv[tid] = 1.f / (ps[tid * 4] + ps[tid * 4 + 1] + ps[tid * 4 + 2] + ps[tid * 4 + 3]);
    __syncthreads();
    // out[i][f] = (sum_j e_ij * xl[j][h*32+f]) * inv[i]; accumulate over h
#pragma unroll
    for (int ii = 0; ii < 2; ++ii) {
      const int i = ig * 2 + ii;
      float a0 = 0.f, a1 = 0.f, a2 = 0.f, a3 = 0.f;
      for (int j = 0; j < 64; ++j) {
        float av = al[i * 68 + j];
        const float4 xv = *(const float4*)&xls[j * 132 + h * 32 + q4 * 4];
        a0 += av * xv.x; a1 += av * xv.y; a2 += av * xv.z; a3 += av * xv.w;
      }
      const float iv = inv[i];
      accH[ii][0] += a0 * iv; accH[ii][1] += a1 * iv;
      accH[ii][2] += a2 * iv; accH[ii][3] += a3 * iv;
    }
  }

  // epilogue: head-mean + bias -> BN -> +skip -> exact GELU; SE partial sums
  float bscale[4], bshift[4], bi[4];
#pragma unroll
  for (int r = 0; r < 4; ++r) {
    int f = q4 * 4 + r;
    float g = bnp[f], be = bnp[32 + f], m = bnp[64 + f], v = bnp[96 + f];
    bscale[r] = g / sqrtf(v + 1e-5f);
    bshift[r] = be - m * bscale[r];
    bi[r] = bias[f];
  }
#pragma unroll
  for (int ii = 0; ii < 2; ++ii) {
    const int i = ig * 2 + ii;
    float res[4];
#pragma unroll
    for (int r = 0; r < 4; ++r) {
      int f = q4 * 4 + r;
      float v = accH[ii][r] * 0.25f + bi[r];
      v = v * bscale[r] + bshift[r];
      float skip;
      if (LAYER == 1) {
        skip = 0.f;
#pragma unroll
        for (int q = 0; q < 16; ++q) skip += Xs[i * 16 + q] * skip_w[f * 16 + q];
      } else {
        skip = Xs[i * 32 + f];
      }
      v += skip;
      v = 0.5f * v * (1.f + erff(v * 0.70710678118654752440f));  // exact gelu
      res[r] = v;
      atomicAdd(&seacc[f], v);
    }
    float4* op = (float4*)&out[(b * 64 + i) * 32 + q4 * 4];
    *op = make_float4(res[0], res[1], res[2], res[3]);
  }
  __syncthreads();
  if (tid < 32) atomicAdd(&gsum[tid], seacc[tid]);
}

// ---------------------------------------------------------------------------
// SE gate: g = sigmoid(relu(mean @ w1^T) @ w2^T)
__global__ void se_kernel(const float* __restrict__ gsum,
                          const float* __restrict__ w1, const float* __restrict__ w2,
                          float* __restrict__ g)
{
  __shared__ float m[32];
  __shared__ float r[8];
  const int tid = threadIdx.x;
  if (tid < 32) m[tid] = gsum[tid] * (1.f / 8192.f);
  __syncthreads();
  if (tid < 8) {
    float a = 0.f;
    for (int f = 0; f < 32; ++f) a += m[f] * w1[tid * 32 + f];
    r[tid] = a > 0.f ? a : 0.f;
  }
  __syncthreads();
  if (tid < 32) {
    float a = 0.f;
    for (int k = 0; k < 8; ++k) a += r[k] * w2[tid * 8 + k];
    g[tid] = 1.f / (1.f + expf(-a));
  }
}

// ---------------------------------------------------------------------------
// pooled = mean_C(tmp2 * g2); out = pooled @ clf_w^T + clf_b
__global__ __launch_bounds__(64) void out_kernel(
    const float* __restrict__ tmp2, const float* __restrict__ g2,
    const float* __restrict__ clf_w, const float* __restrict__ clf_b,
    float* __restrict__ outp)
{
  __shared__ float pl[32];
  const int b = blockIdx.x, tid = threadIdx.x;
  if (tid < 32) {
    float a = 0.f;
    for (int n = 0; n < 64; ++n) a += tmp2[(b * 64 + n) * 32 + tid];
    pl[tid] = a * (1.f / 64.f) * g2[tid];
  }
  __syncthreads();
  if (tid < 2) {
    float a = clf_b[tid];
    for (int f = 0; f < 32; ++f) a += pl[f] * clf_w[tid * 32 + f];
    outp[b * 2 + tid] = a;
  }
}

// ---------------------------------------------------------------------------
extern "C" void kernel_launch(void* const* d_in, const int* in_sizes, int n_in,
                              void* d_out, int out_size, void* d_ws, size_t ws_size,
                              hipStream_t stream)
{
  const float* x          = (const float*)d_in[0];
  const int*   edges      = (const int*)d_in[1];
  const float* conv1_w    = (const float*)d_in[2];
  const float* bn_c1      = (const float*)d_in[3];
  const float* dw_w       = (const float*)d_in[4];
  const float* bn_c2      = (const float*)d_in[5];
  const float* sdw_w      = (const float*)d_in[6];
  const float* spw_w      = (const float*)d_in[7];
  const float* bn_c3      = (const float*)d_in[8];
  const float* node_embed = (const float*)d_in[9];
  const float* gat1_w     = (const float*)d_in[10];
  const float* gat1_asrc  = (const float*)d_in[11];
  const float* gat1_adst  = (const float*)d_in[12];
  const float* gat1_bias  = (const float*)d_in[13];
  const float* bn_g1      = (const float*)d_in[14];
  const float* skip1_w    = (const float*)d_in[15];
  const float* se1_w1     = (const float*)d_in[16];
  const float* se1_w2     = (const float*)d_in[17];
  const float* gat2_w     = (const float*)d_in[18];
  const float* gat2_asrc  = (const float*)d_in[19];
  const float* gat2_adst  = (const float*)d_in[20];
  const float* gat2_bias  = (const float*)d_in[21];
  const float* bn_g2      = (const float*)d_in[22];
  const float* se2_w1     = (const float*)d_in[23];
  const float* se2_w2     = (const float*)d_in[24];
  const float* clf_w      = (const float*)d_in[25];
  const float* clf_b      = (const float*)d_in[26];

  float* ws    = (float*)d_ws;
  float* feats = ws;               // 131072 floats  [B*C, 16]
  float* Mlog  = ws + 131072;      // 4096           [64, 64]
  float* tmp1  = ws + 135168;      // 262144         [B*C, 32]
  float* tmp2  = ws + 397312;      // 262144         [B*C, 32]
  float* sums  = ws + 659456;      // 64 (sum1[32] | sum2[32])
  float* g1    = ws + 659520;      // 32
  float* g2    = ws + 659552;      // 32

  init_kernel<<<1, 64, 0, stream>>>(sums);
  feat_kernel<<<Bn * Cn, 256, 0, stream>>>(x, conv1_w, bn_c1, dw_w, bn_c2,
                                           sdw_w, spw_w, bn_c3, feats);
  graph_kernel<<<1, 256, 0, stream>>>(node_embed, edges, Mlog);
  gat_kernel<16, 1><<<Bn, 256, 0, stream>>>(feats, nullptr, gat1_w, gat1_asrc,
                                            gat1_adst, gat1_bias, bn_g1, skip1_w,
                                            Mlog, tmp1, sums);
  se_kernel<<<1, 64, 0, stream>>>(sums, se1_w1, se1_w2, g1);
  gat_kernel<32, 2><<<Bn, 256, 0, stream>>>(tmp1, g1, gat2_w, gat2_asrc,
                                            gat2_adst, gat2_bias, bn_g2, nullptr,
                                            Mlog, tmp2, sums + 32);
  se_kernel<<<1, 64, 0, stream>>>(sums + 32, se2_w1, se2_w2, g2);
  out_kernel<<<Bn, 64, 0, stream>>>(tmp2, g2, clf_w, clf_b, (float*)d_out);
}

// Round 3
// 336.803 us; speedup vs baseline: 2.0740x; 2.0740x over previous
//
#include <hip/hip_runtime.h>
#include <math.h>

#define Bn 128
#define Cn 64
#define Tn 500
#define P1 516   // s1 row pitch: 4 front pad + 512 data; 516 % 8 == 4 -> conflict-free b128 phases

__device__ __forceinline__ float elu_f(float v) {
  return v > 0.f ? v : (__expf(v) - 1.f);
}

// ---------------------------------------------------------------------------
// Stage 1: EEG feature extractor. One block per (b,c) signal.
// conv1 (K=25) -> BN/ELU -> dw (K=3) -> BN/ELU -> sdw (K=3) -> pointwise 16x16
// -> BN/ELU -> mean over t. Single in-place LDS buffer; windows read as
// ds_read_b128 (broadcast across the 16 o-lanes); pw reads a transposed
// sT[t][16] aliased over s1.
__global__ __launch_bounds__(256, 4) void feat_kernel(
    const float* __restrict__ x, const float* __restrict__ w_conv1,
    const float* __restrict__ bn1, const float* __restrict__ w_dw,
    const float* __restrict__ bn2, const float* __restrict__ w_sdw,
    const float* __restrict__ w_spw, const float* __restrict__ bn3,
    float* __restrict__ feats)
{
  __shared__ float s1[16 * P1 + 16];  // 8272 floats; also aliased as sT[512*16]
  __shared__ float xs[536];           // x padded: phys = logical t + 12
  __shared__ float red[64];
  const int n = blockIdx.x;
  const int tid = threadIdx.x;
  const int o = tid & 15;
  const int tq = tid >> 4;            // 0..15

  // ---- stage x into LDS, zero pads and s1 front pads ----
  if (tid < 125) {
    const float4* xg = (const float4*)(x + n * Tn);
    *(float4*)&xs[12 + tid * 4] = xg[tid];
  }
  if (tid < 12) xs[tid] = 0.f;
  if (tid < 24) xs[512 + tid] = 0.f;            // logical t in [500, 524)
  if (tid < 64) s1[(tid >> 2) * P1 + (tid & 3)] = 0.f;  // t = -4..-1 halo

  // conv1 weights + BN for this thread's channel
  float w1[25];
#pragma unroll
  for (int k = 0; k < 25; ++k) w1[k] = w_conv1[o * 25 + k];
  float sc1 = bn1[o] * rsqrtf(bn1[48 + o] + 1e-5f);
  float sh1 = bn1[16 + o] - bn1[32 + o] * sc1;

  __syncthreads();

  // ---- conv1 + BN + ELU -> s1 ----
#pragma unroll
  for (int i = 0; i < 8; ++i) {
    const int tb = tq * 4 + i * 64;
    float xw[28];
    const float4* xp = (const float4*)&xs[tb];   // phys tb = logical tb-12
#pragma unroll
    for (int c = 0; c < 7; ++c) {
      float4 v = xp[c];
      xw[4 * c] = v.x; xw[4 * c + 1] = v.y; xw[4 * c + 2] = v.z; xw[4 * c + 3] = v.w;
    }
    float4 res;
    float* rp = &res.x;
#pragma unroll
    for (int r = 0; r < 4; ++r) {
      float acc = 0.f;
#pragma unroll
      for (int k = 0; k < 25; ++k) acc += xw[r + k] * w1[k];
      float v = elu_f(acc * sc1 + sh1);
      rp[r] = (tb + r < Tn) ? v : 0.f;
    }
    *(float4*)&s1[o * P1 + 4 + tb] = res;
  }

  // ---- depthwise K=3 + BN + ELU (in place: read all -> sync -> write) ----
  float wd0 = w_dw[o * 3], wd1 = w_dw[o * 3 + 1], wd2 = w_dw[o * 3 + 2];
  float sc2 = bn2[o] * rsqrtf(bn2[48 + o] + 1e-5f);
  float sh2 = bn2[16 + o] - bn2[32 + o] * sc2;
  float dres[32];
  __syncthreads();
#pragma unroll
  for (int i = 0; i < 8; ++i) {
    const int tb = tq * 4 + i * 64;
    const float* row = &s1[o * P1 + 4 + tb];
    float4 A = *(const float4*)(row - 4);
    float4 B = *(const float4*)(row);
    float4 C = *(const float4*)(row + 4);
    float win[6] = {A.w, B.x, B.y, B.z, B.w, C.x};
#pragma unroll
    for (int r = 0; r < 4; ++r) {
      float acc = win[r] * wd0 + win[r + 1] * wd1 + win[r + 2] * wd2;
      float v = elu_f(acc * sc2 + sh2);
      dres[i * 4 + r] = (tb + r < Tn) ? v : 0.f;
    }
  }
  __syncthreads();
#pragma unroll
  for (int i = 0; i < 8; ++i) {
    const int tb = tq * 4 + i * 64;
    *(float4*)&s1[o * P1 + 4 + tb] = *(float4*)&dres[i * 4];
  }

  // ---- separable depthwise K=3 (no activation), result -> registers ----
  float we0 = w_sdw[o * 3], we1 = w_sdw[o * 3 + 1], we2 = w_sdw[o * 3 + 2];
  float sres[32];
  __syncthreads();
#pragma unroll
  for (int i = 0; i < 8; ++i) {
    const int tb = tq * 4 + i * 64;
    const float* row = &s1[o * P1 + 4 + tb];
    float4 A = *(const float4*)(row - 4);
    float4 B = *(const float4*)(row);
    float4 C = *(const float4*)(row + 4);
    float win[6] = {A.w, B.x, B.y, B.z, B.w, C.x};
#pragma unroll
    for (int r = 0; r < 4; ++r) {
      float acc = win[r] * we0 + win[r + 1] * we1 + win[r + 2] * we2;
      sres[i * 4 + r] = (tb + r < Tn) ? acc : 0.f;
    }
  }
  __syncthreads();
  // transpose into sT[t][16] (aliases s1; all s1 row reads are done)
  {
    float* sT = s1;
#pragma unroll
    for (int i = 0; i < 8; ++i) {
      const int tb = tq * 4 + i * 64;
#pragma unroll
      for (int r = 0; r < 4; ++r) sT[(tb + r) * 16 + o] = sres[i * 4 + r];
    }
  }

  // ---- pointwise 16->16 + BN + ELU + mean over t ----
  const int oq = tid & 3, tg = tid >> 2;   // channels oq*4..+3, t = tg + 64*tt
  float wp[64];
#pragma unroll
  for (int r = 0; r < 4; ++r)
#pragma unroll
    for (int c = 0; c < 4; ++c)
      *(float4*)&wp[r * 16 + c * 4] = *(const float4*)&w_spw[(oq * 4 + r) * 16 + c * 4];
  float sc3[4], sh3[4];
#pragma unroll
  for (int r = 0; r < 4; ++r) {
    int ch = oq * 4 + r;
    sc3[r] = bn3[ch] * rsqrtf(bn3[48 + ch] + 1e-5f);
    sh3[r] = bn3[16 + ch] - bn3[32 + ch] * sc3[r];
  }
  float acc[4] = {0.f, 0.f, 0.f, 0.f};
  __syncthreads();
  {
    const float* sT = s1;
#pragma unroll
    for (int tt = 0; tt < 8; ++tt) {
      const int t = tg + 64 * tt;
      if (t < Tn) {
        float v[16];
#pragma unroll
        for (int c = 0; c < 4; ++c) *(float4*)&v[4 * c] = *(const float4*)&sT[t * 16 + 4 * c];
#pragma unroll
        for (int r = 0; r < 4; ++r) {
          float s = 0.f;
#pragma unroll
          for (int q = 0; q < 16; ++q) s += v[q] * wp[r * 16 + q];
          acc[r] += elu_f(s * sc3[r] + sh3[r]);
        }
      }
    }
  }
  // reduce over the 16 tg values within the wave (lane bits 2..5)
#pragma unroll
  for (int d = 4; d <= 32; d <<= 1) {
#pragma unroll
    for (int r = 0; r < 4; ++r) acc[r] += __shfl_xor(acc[r], d, 64);
  }
  if ((tid & 63) < 4) {
#pragma unroll
    for (int r = 0; r < 4; ++r) red[(tid >> 6) * 16 + oq * 4 + r] = acc[r];
  }
  __syncthreads();
  if (tid < 16)
    feats[n * 16 + tid] =
        (red[tid] + red[16 + tid] + red[32 + tid] + red[48 + tid]) * (1.f / 500.f);
}

// ---------------------------------------------------------------------------
// Graph construction: Mlog[i][j] = log(M) if M>0 else -inf; also zeroes gsum.
__global__ __launch_bounds__(256) void graph_kernel(
    const float* __restrict__ node_embed, const int* __restrict__ edges,
    float* __restrict__ Mlog, float* __restrict__ gsum)
{
  __shared__ float ne[64 * 16];
  __shared__ float Arow[64 * 64];
  __shared__ float Ms[64 * 64];
  __shared__ float rs[64];
  const int tid = threadIdx.x;
  if (tid < 64) gsum[tid] = 0.f;
  for (int idx = tid; idx < 64 * 16; idx += 256) ne[idx] = node_embed[idx];
  for (int idx = tid; idx < 4096; idx += 256) Ms[idx] = 0.f;
  __syncthreads();
  for (int idx = tid; idx < 4096; idx += 256) {
    int i = idx >> 6, j = idx & 63;
    float a = 0.f;
#pragma unroll
    for (int f = 0; f < 16; ++f) a += ne[i * 16 + f] * ne[j * 16 + f];
    Arow[idx] = a > 0.f ? a : 0.f;
  }
  {
    int e0 = edges[tid];
    int e1 = edges[256 + tid];
    __syncthreads();
    atomicAdd(&Ms[e0 * 64 + e1], 1.f);
  }
  __syncthreads();
  if (tid < 64) {
    float s = 0.f;
    for (int j = 0; j < 64; ++j) s += Arow[tid * 64 + j];
    rs[tid] = s + 1e-6f;
  }
  __syncthreads();
  for (int idx = tid; idx < 4096; idx += 256) {
    int i = idx >> 6, j = idx & 63;
    float dyn = (Arow[idx] / rs[i] > 0.1f) ? 1.f : 0.f;
    float M = (i == j) ? 1.f : (Ms[idx] + dyn);
    Mlog[idx] = (M > 0.f) ? logf(M) : -INFINITY;
  }
}

// ---------------------------------------------------------------------------
// One GAT layer fused with BN + skip + GELU + SE partial sums. Block per b.
template <int FIN, int LAYER>
__global__ __launch_bounds__(256) void gat_kernel(
    const float* __restrict__ Xsrc, const float* __restrict__ gate,
    const float* __restrict__ W, const float* __restrict__ a_src,
    const float* __restrict__ a_dst, const float* __restrict__ bias,
    const float* __restrict__ bnp, const float* __restrict__ skip_w,
    const float* __restrict__ Mlog,
    float* __restrict__ out, float* __restrict__ gsum)
{
  __shared__ float Xs[64 * FIN];
  __shared__ float xls[64 * 132];
  __shared__ float sS[64 * 4];
  __shared__ float dS[64 * 4];
  __shared__ float al[64 * 68];
  __shared__ float pm[256];
  __shared__ float rm[64];
  __shared__ float ps[256];
  __shared__ float inv[64];
  __shared__ float seacc[32];
  const int b = blockIdx.x;
  const int tid = threadIdx.x;

  if (tid < 32) seacc[tid] = 0.f;
  for (int idx = tid; idx < 64 * FIN; idx += 256) {
    float v = Xsrc[b * 64 * FIN + idx];
    if (LAYER == 2) v *= gate[idx % FIN];
    Xs[idx] = v;
  }
  __syncthreads();

  {
    const int fo = tid & 127, half = tid >> 7;
    float wcol[FIN];
#pragma unroll
    for (int q = 0; q < FIN; ++q) wcol[q] = W[q * 128 + fo];
    for (int nn = half; nn < 64; nn += 2) {
      float acc = 0.f;
#pragma unroll
      for (int q = 0; q < FIN; ++q) acc += Xs[nn * FIN + q] * wcol[q];
      xls[nn * 132 + fo] = acc;
    }
  }
  __syncthreads();

  {
    const int nn = tid >> 2, h = tid & 3;
    float s = 0.f, d = 0.f;
    for (int q = 0; q < 32; ++q) {
      float xv = xls[nn * 132 + h * 32 + q];
      s += xv * a_src[h * 32 + q];
      d += xv * a_dst[h * 32 + q];
    }
    sS[nn * 4 + h] = s;
    dS[nn * 4 + h] = d;
  }

  float accH[2][4];
#pragma unroll
  for (int ii = 0; ii < 2; ++ii)
#pragma unroll
    for (int r = 0; r < 4; ++r) accH[ii][r] = 0.f;

  const int q4 = tid & 7;
  const int ig = tid >> 3;

  for (int h = 0; h < 4; ++h) {
    __syncthreads();
    for (int idx = tid; idx < 4096; idx += 256) {
      int i = idx >> 6, j = idx & 63;
      float e = dS[i * 4 + h] + sS[j * 4 + h];
      e = e >= 0.f ? e : 0.2f * e;
      al[i * 68 + j] = e + Mlog[idx];
    }
    __syncthreads();
    {
      const int i = tid >> 2, c = tid & 3;
      float mx = -INFINITY;
      for (int jj = 0; jj < 16; ++jj) mx = fmaxf(mx, al[i * 68 + c * 16 + jj]);
      pm[tid] = mx;
    }
    __syncthreads();
    if (tid < 64)
      rm[tid] = fmaxf(fmaxf(pm[tid * 4], pm[tid * 4 + 1]),
                      fmaxf(pm[tid * 4 + 2], pm[tid * 4 + 3]));
    __syncthreads();
    {
      const int i = tid >> 2, c = tid & 3;
      float r = rm[i], sm = 0.f;
      for (int jj = 0; jj < 16; ++jj) {
        float v = __expf(al[i * 68 + c * 16 + jj] - r);
        al[i * 68 + c * 16 + jj] = v;
        sm += v;
      }
      ps[tid] = sm;
    }
    __syncthreads();
    if (tid < 64)
      inv[tid] = 1.f / (ps[tid * 4] + ps[tid * 4 + 1] + ps[tid * 4 + 2] + ps[tid * 4 + 3]);
    __syncthreads();
#pragma unroll
    for (int ii = 0; ii < 2; ++ii) {
      const int i = ig * 2 + ii;
      float a0 = 0.f, a1 = 0.f, a2 = 0.f, a3 = 0.f;
      for (int j = 0; j < 64; ++j) {
        float av = al[i * 68 + j];
        const float4 xv = *(const float4*)&xls[j * 132 + h * 32 + q4 * 4];
        a0 += av * xv.x; a1 += av * xv.y; a2 += av * xv.z; a3 += av * xv.w;
      }
      const float iv = inv[i];
      accH[ii][0] += a0 * iv; accH[ii][1] += a1 * iv;
      accH[ii][2] += a2 * iv; accH[ii][3] += a3 * iv;
    }
  }

  float bscale[4], bshift[4], bi[4];
#pragma unroll
  for (int r = 0; r < 4; ++r) {
    int f = q4 * 4 + r;
    float g = bnp[f], be = bnp[32 + f], m = bnp[64 + f], v = bnp[96 + f];
    bscale[r] = g * rsqrtf(v + 1e-5f);
    bshift[r] = be - m * bscale[r];
    bi[r] = bias[f];
  }
#pragma unroll
  for (int ii = 0; ii < 2; ++ii) {
    const int i = ig * 2 + ii;
    float res[4];
#pragma unroll
    for (int r = 0; r < 4; ++r) {
      int f = q4 * 4 + r;
      float v = accH[ii][r] * 0.25f + bi[r];
      v = v * bscale[r] + bshift[r];
      float skip;
      if (LAYER == 1) {
        skip = 0.f;
#pragma unroll
        for (int q = 0; q < 16; ++q) skip += Xs[i * 16 + q] * skip_w[f * 16 + q];
      } else {
        skip = Xs[i * 32 + f];
      }
      v += skip;
      v = 0.5f * v * (1.f + erff(v * 0.70710678118654752440f));
      res[r] = v;
      atomicAdd(&seacc[f], v);
    }
    float4* op = (float4*)&out[(b * 64 + i) * 32 + q4 * 4];
    *op = make_float4(res[0], res[1], res[2], res[3]);
  }
  __syncthreads();
  if (tid < 32) atomicAdd(&gsum[tid], seacc[tid]);
}

// ---------------------------------------------------------------------------
__global__ void se_kernel(const float* __restrict__ gsum,
                          const float* __restrict__ w1, const float* __restrict__ w2,
                          float* __restrict__ g)
{
  __shared__ float m[32];
  __shared__ float r[8];
  const int tid = threadIdx.x;
  if (tid < 32) m[tid] = gsum[tid] * (1.f / 8192.f);
  __syncthreads();
  if (tid < 8) {
    float a = 0.f;
    for (int f = 0; f < 32; ++f) a += m[f] * w1[tid * 32 + f];
    r[tid] = a > 0.f ? a : 0.f;
  }
  __syncthreads();
  if (tid < 32) {
    float a = 0.f;
    for (int k = 0; k < 8; ++k) a += r[k] * w2[tid * 8 + k];
    g[tid] = 1.f / (1.f + __expf(-a));
  }
}

// ---------------------------------------------------------------------------
__global__ __launch_bounds__(64) void out_kernel(
    const float* __restrict__ tmp2, const float* __restrict__ g2,
    const float* __restrict__ clf_w, const float* __restrict__ clf_b,
    float* __restrict__ outp)
{
  __shared__ float pl[32];
  const int b = blockIdx.x, tid = threadIdx.x;
  if (tid < 32) {
    float a = 0.f;
    for (int n = 0; n < 64; ++n) a += tmp2[(b * 64 + n) * 32 + tid];
    pl[tid] = a * (1.f / 64.f) * g2[tid];
  }
  __syncthreads();
  if (tid < 2) {
    float a = clf_b[tid];
    for (int f = 0; f < 32; ++f) a += pl[f] * clf_w[tid * 32 + f];
    outp[b * 2 + tid] = a;
  }
}

// ---------------------------------------------------------------------------
extern "C" void kernel_launch(void* const* d_in, const int* in_sizes, int n_in,
                              void* d_out, int out_size, void* d_ws, size_t ws_size,
                              hipStream_t stream)
{
  const float* x          = (const float*)d_in[0];
  const int*   edges      = (const int*)d_in[1];
  const float* conv1_w    = (const float*)d_in[2];
  const float* bn_c1      = (const float*)d_in[3];
  const float* dw_w       = (const float*)d_in[4];
  const float* bn_c2      = (const float*)d_in[5];
  const float* sdw_w      = (const float*)d_in[6];
  const float* spw_w      = (const float*)d_in[7];
  const float* bn_c3      = (const float*)d_in[8];
  const float* node_embed = (const float*)d_in[9];
  const float* gat1_w     = (const float*)d_in[10];
  const float* gat1_asrc  = (const float*)d_in[11];
  const float* gat1_adst  = (const float*)d_in[12];
  const float* gat1_bias  = (const float*)d_in[13];
  const float* bn_g1      = (const float*)d_in[14];
  const float* skip1_w    = (const float*)d_in[15];
  const float* se1_w1     = (const float*)d_in[16];
  const float* se1_w2     = (const float*)d_in[17];
  const float* gat2_w     = (const float*)d_in[18];
  const float* gat2_asrc  = (const float*)d_in[19];
  const float* gat2_adst  = (const float*)d_in[20];
  const float* gat2_bias  = (const float*)d_in[21];
  const float* bn_g2      = (const float*)d_in[22];
  const float* se2_w1     = (const float*)d_in[23];
  const float* se2_w2     = (const float*)d_in[24];
  const float* clf_w      = (const float*)d_in[25];
  const float* clf_b      = (const float*)d_in[26];

  float* ws    = (float*)d_ws;
  float* feats = ws;               // 131072 floats  [B*C, 16]
  float* Mlog  = ws + 131072;      // 4096           [64, 64]
  float* tmp1  = ws + 135168;      // 262144         [B*C, 32]
  float* tmp2  = ws + 397312;      // 262144         [B*C, 32]
  float* sums  = ws + 659456;      // 64 (sum1[32] | sum2[32])
  float* g1    = ws + 659520;      // 32
  float* g2    = ws + 659552;      // 32

  feat_kernel<<<Bn * Cn, 256, 0, stream>>>(x, conv1_w, bn_c1, dw_w, bn_c2,
                                           sdw_w, spw_w, bn_c3, feats);
  graph_kernel<<<1, 256, 0, stream>>>(node_embed, edges, Mlog, sums);
  gat_kernel<16, 1><<<Bn, 256, 0, stream>>>(feats, nullptr, gat1_w, gat1_asrc,
                                            gat1_adst, gat1_bias, bn_g1, skip1_w,
                                            Mlog, tmp1, sums);
  se_kernel<<<1, 64, 0, stream>>>(sums, se1_w1, se1_w2, g1);
  gat_kernel<32, 2><<<Bn, 256, 0, stream>>>(tmp1, g1, gat2_w, gat2_asrc,
                                            gat2_adst, gat2_bias, bn_g2, nullptr,
                                            Mlog, tmp2, sums + 32);
  se_kernel<<<1, 64, 0, stream>>>(sums + 32, se2_w1, se2_w2, g2);
  out_kernel<<<Bn, 64, 0, stream>>>(tmp2, g2, clf_w, clf_b, (float*)d_out);
}